// Round 1
// baseline (186.295 us; speedup 1.0000x reference)
//
#include <hip/hip_runtime.h>

// TemporalContrastiveLoss: B=512, T=256, D=256, temperature 0.1.
// K1: normalize rows (fp32) -> bf16 into ws.
// K2: per-batch S=F*F^T via mfma_f32_32x32x16_bf16 from swizzled LDS,
//     fused row-wise logsumexp(10*S) minus super-diagonal, per-batch partial.
// K3: deterministic reduction of 512 partials -> mean scalar.

typedef float f32x4  __attribute__((ext_vector_type(4)));
typedef float f32x16 __attribute__((ext_vector_type(16)));
typedef unsigned int   u32x4 __attribute__((ext_vector_type(4)));
typedef unsigned short u16x4 __attribute__((ext_vector_type(4)));
typedef __bf16 bf16x8 __attribute__((ext_vector_type(8)));

#define NB   512
#define NT   256
#define ND   256

__device__ __forceinline__ unsigned short f2bf_rne(float f) {
  unsigned int u = __float_as_uint(f);
  return (unsigned short)((u + 0x7fffu + ((u >> 16) & 1u)) >> 16);
}

// ---------------- K1: one wave per row: normalize + cast to bf16 ----------
__global__ __launch_bounds__(256) void norm_bf16_kernel(
    const float* __restrict__ x, unsigned short* __restrict__ fn) {
  const int wave = threadIdx.x >> 6;
  const int lane = threadIdx.x & 63;
  const long long row = (long long)blockIdx.x * 4 + wave;   // 131072 rows
  const f32x4* xr = (const f32x4*)(x + row * ND);
  f32x4 v = xr[lane];                                       // 16B/lane, coalesced
  float ss = v.x * v.x + v.y * v.y + v.z * v.z + v.w * v.w;
#pragma unroll
  for (int d = 1; d < 64; d <<= 1) ss += __shfl_xor(ss, d);
  const float inv = rsqrtf(fmaxf(ss, 1e-24f));              // eps=1e-12 on norm
  u16x4 o;
  o.x = f2bf_rne(v.x * inv);
  o.y = f2bf_rne(v.y * inv);
  o.z = f2bf_rne(v.z * inv);
  o.w = f2bf_rne(v.w * inv);
  ((u16x4*)(fn + row * ND))[lane] = o;                      // 8B/lane, coalesced
}

// ---------------- K2: per-batch GEMM + fused LSE --------------------------
// LDS layout: [256 rows][32 chunks of 16B], chunk slot = gc ^ (row & 7)
// (byte ^= (row&7)<<4): breaks the 16-way bank conflict of stride-512B
// ds_read_b128 fragment reads.
__global__ __launch_bounds__(256, 1) void sim_lse_kernel(
    const unsigned short* __restrict__ fn, float* __restrict__ partial) {
  __shared__ u32x4 lds4[NT * 32];   // 128 KiB
  __shared__ float red[4];

  const int b = blockIdx.x;
  const int t = threadIdx.x;

  // stage F[b] (bf16, already normalized) into swizzled LDS
  const u32x4* g = (const u32x4*)(fn + (long long)b * (NT * ND));
#pragma unroll 8
  for (int i = 0; i < 32; ++i) {
    int f  = i * 256 + t;           // 16B chunk index, 8192 total
    int r  = f >> 5;
    int gc = f & 31;
    lds4[r * 32 + (gc ^ (r & 7))] = g[f];
  }
  __syncthreads();

  const int lane = t & 63;
  const int wave = t >> 6;
  const int lo5  = lane & 31;
  const int hi   = lane >> 5;
  const int sx   = lo5 & 7;         // swizzle xor (rows of a frag: base+lo5)

  // chunk offset within a row for (kb, hi), pre-xored with the row swizzle:
  // slot = ((kb*2)|hi) ^ sx  ==  ((kb*2) ^ (sx&6)) + (hi ^ (sx&1))
  int kbo[16];
#pragma unroll
  for (int kb = 0; kb < 16; ++kb)
    kbo[kb] = ((kb * 2) ^ (sx & 6)) + (hi ^ (sx & 1));

  float local = 0.0f;

#pragma unroll 1
  for (int strip = 0; strip < 2; ++strip) {
    const int row_base = wave * 64 + strip * 32;   // this wave's 32 S-rows
    const int arow = row_base + lo5;
    const u32x4* abase = &lds4[arow * 32];

    // A fragments: rows row_base+lo5, k = kb*16 + hi*8 + [0..8)
    bf16x8 afrag[16];
#pragma unroll
    for (int kb = 0; kb < 16; ++kb)
      afrag[kb] = __builtin_bit_cast(bf16x8, abase[kbo[kb]]);

    f32x16 acc[8];
#pragma unroll
    for (int ct = 0; ct < 8; ++ct)
#pragma unroll
      for (int e = 0; e < 16; ++e) acc[ct][e] = 0.0f;

    // K-loop: 16 k-blocks x 8 col-tiles; 8 independent acc chains
#pragma unroll
    for (int kb = 0; kb < 16; ++kb) {
#pragma unroll
      for (int ct = 0; ct < 8; ++ct) {
        const u32x4* bbase = &lds4[(ct * 32 + lo5) * 32];
        bf16x8 bfrag = __builtin_bit_cast(bf16x8, bbase[kbo[kb]]);
        acc[ct] = __builtin_amdgcn_mfma_f32_32x32x16_bf16(
            afrag[kb], bfrag, acc[ct], 0, 0, 0);
      }
    }

    // Row-wise LSE of logits = 10*acc over 256 cols, minus target logit.
    // C/D layout (measured): col = ct*32 + (lane&31),
    //                        row = (reg&3) + 8*(reg>>2) + 4*(lane>>5)
#pragma unroll
    for (int reg = 0; reg < 16; ++reg) {
      const int r = (reg & 3) + 8 * (reg >> 2) + 4 * hi;
      const int q = row_base + r;                  // global S-row
      float m = -3.4e38f;
#pragma unroll
      for (int ct = 0; ct < 8; ++ct) m = fmaxf(m, acc[ct][reg]);
#pragma unroll
      for (int d = 1; d < 32; d <<= 1) m = fmaxf(m, __shfl_xor(m, d));
      float s = 0.0f;
#pragma unroll
      for (int ct = 0; ct < 8; ++ct) s += __expf((acc[ct][reg] - m) * 10.0f);
#pragma unroll
      for (int d = 1; d < 32; d <<= 1) s += __shfl_xor(s, d);
      if (q < NT - 1) {
        if (lo5 == 0) local += 10.0f * m + __logf(s);   // lse of this row
        const int tc = q + 1;                           // target col
        if (lo5 == (tc & 31)) {
          float tv = 0.0f;
#pragma unroll
          for (int ct = 0; ct < 8; ++ct)
            if (ct == (tc >> 5)) tv = acc[ct][reg];
          local -= 10.0f * tv;
        }
      }
    }
  }

  // block reduction of per-thread partials
#pragma unroll
  for (int d = 1; d < 64; d <<= 1) local += __shfl_xor(local, d);
  if (lane == 0) red[wave] = local;
  __syncthreads();
  if (t == 0) partial[b] = red[0] + red[1] + red[2] + red[3];
}

// ---------------- K3: 512 partials -> mean (deterministic) ----------------
__global__ __launch_bounds__(256) void reduce_kernel(
    const float* __restrict__ partial, float* __restrict__ out) {
  const int t = threadIdx.x;
  float v = partial[t] + partial[t + 256];
#pragma unroll
  for (int d = 1; d < 64; d <<= 1) v += __shfl_xor(v, d);
  __shared__ float red[4];
  if ((t & 63) == 0) red[t >> 6] = v;
  __syncthreads();
  if (t == 0)
    out[0] = (red[0] + red[1] + red[2] + red[3]) * (1.0f / (float)(NB * (NT - 1)));
}

extern "C" void kernel_launch(void* const* d_in, const int* in_sizes, int n_in,
                              void* d_out, int out_size, void* d_ws, size_t ws_size,
                              hipStream_t stream) {
  (void)in_sizes; (void)n_in; (void)out_size; (void)ws_size;
  const float* x = (const float*)d_in[0];
  float* out = (float*)d_out;
  unsigned short* fn = (unsigned short*)d_ws;                       // 64 MiB bf16
  float* partial = (float*)((char*)d_ws + (size_t)NB * NT * ND * 2); // +2 KiB

  hipLaunchKernelGGL(norm_bf16_kernel, dim3((NB * NT) / 4), dim3(256), 0, stream,
                     x, fn);
  hipLaunchKernelGGL(sim_lse_kernel, dim3(NB), dim3(256), 0, stream, fn, partial);
  hipLaunchKernelGGL(reduce_kernel, dim3(1), dim3(256), 0, stream, partial, out);
}

// Round 2
// 90.745 us; speedup vs baseline: 2.0529x; 2.0529x over previous
//
#include <hip/hip_runtime.h>

// TemporalContrastiveLoss: B=512, T=256, D=256, temperature 0.1.
// Fused kernel: per-batch block (512 thr) normalizes F (fp32->bf16) into
// swizzled LDS, computes S=F*F^T via 64x64 wave-tiles of mfma_32x32x16_bf16,
// fused per-tile partial LSE (m,s) -> LDS merge -> per-batch partial.
// K3: deterministic 512->1 reduction.

typedef float f32x4  __attribute__((ext_vector_type(4)));
typedef float f32x16 __attribute__((ext_vector_type(16)));
typedef unsigned int   u32x2 __attribute__((ext_vector_type(2)));
typedef unsigned int   u32x4 __attribute__((ext_vector_type(4)));
typedef __bf16 bf16x8 __attribute__((ext_vector_type(8)));

#define NB   512
#define NT   256
#define ND   256

__device__ __forceinline__ unsigned int f2bf_rne(float f) {
  unsigned int u = __float_as_uint(f);
  return (u + 0x7fffu + ((u >> 16) & 1u)) >> 16;
}

// ---------------- fused: normalize + GEMM + LSE ---------------------------
// LDS matrix layout: [256 rows][32 chunks of 16B], chunk slot = c ^ (row & 7)
// (byte ^= (row&7)<<4): breaks the 16-way bank conflict of stride-512B
// ds_read_b128 fragment reads.
__global__ __launch_bounds__(512, 2) void fused_kernel(
    const float* __restrict__ x, float* __restrict__ partial) {
  __shared__ u32x4 lds4[NT * 32];      // 128 KiB bf16 matrix
  __shared__ float mbuf[NT][4];        // per-row, per-64col-group max (x10 scale)
  __shared__ float sbuf[NT][4];        // per-row, per-64col-group sum exp
  __shared__ float tbuf[NT];           // per-row target logit (x10 scale)
  __shared__ float redbuf[8];

  const int b    = blockIdx.x;
  const int t    = threadIdx.x;
  const int wave = t >> 6;
  const int lane = t & 63;

  // ---- phase 1: normalize 32 rows per wave, RNE->bf16, swizzled LDS store
  {
    const f32x4* xb = (const f32x4*)(x + (size_t)b * (NT * ND));
    unsigned int* l32 = (unsigned int*)lds4;
#pragma unroll 8
    for (int i = 0; i < 32; ++i) {
      const int r = wave * 32 + i;
      f32x4 v = xb[r * 64 + lane];                    // 16B/lane, coalesced
      float ss = v.x * v.x + v.y * v.y + v.z * v.z + v.w * v.w;
#pragma unroll
      for (int d = 1; d < 64; d <<= 1) ss += __shfl_xor(ss, d);
      const float inv = rsqrtf(fmaxf(ss, 1e-24f));    // eps=1e-12 on norm
      u32x2 o;
      o.x = f2bf_rne(v.x * inv) | (f2bf_rne(v.y * inv) << 16);
      o.y = f2bf_rne(v.z * inv) | (f2bf_rne(v.w * inv) << 16);
      // lane holds 8B = chunk c=lane>>1, half lane&1; swizzle slot = c^(r&7)
      const int slot = (lane >> 1) ^ (r & 7);
      *(u32x2*)&l32[r * 128 + slot * 4 + (lane & 1) * 2] = o;
    }
  }
  __syncthreads();

  // ---- phase 2: GEMM 64x64 wave-tiles + per-tile partial LSE
  const int lo5 = lane & 31;
  const int hi  = lane >> 5;
  const int sx  = lo5 & 7;             // frag rows are base+lo5 -> row&7 = sx

  // chunk slot within a row for k-block kb, this lane: (kb*2|hi) ^ sx
  int kbo[16];
#pragma unroll
  for (int kb = 0; kb < 16; ++kb)
    kbo[kb] = ((kb * 2) ^ (sx & 6)) | (hi ^ (sx & 1));

#pragma unroll 1
  for (int ti = 0; ti < 2; ++ti) {
    const int tile = wave + ti * 8;     // 16 tiles: (tr,tc) in 4x4 grid
    const int tr = tile >> 2, tc = tile & 3;
    const int R = tr * 64, C = tc * 64;
    const int ar0 = (R + lo5) * 32, ar1 = (R + 32 + lo5) * 32;
    const int br0 = (C + lo5) * 32, br1 = (C + 32 + lo5) * 32;

    f32x16 a00, a01, a10, a11;
#pragma unroll
    for (int e = 0; e < 16; ++e) { a00[e] = 0.f; a01[e] = 0.f; a10[e] = 0.f; a11[e] = 0.f; }

#pragma unroll
    for (int kb = 0; kb < 16; ++kb) {
      const int ko = kbo[kb];
      bf16x8 fa0 = __builtin_bit_cast(bf16x8, lds4[ar0 + ko]);
      bf16x8 fa1 = __builtin_bit_cast(bf16x8, lds4[ar1 + ko]);
      bf16x8 fb0 = __builtin_bit_cast(bf16x8, lds4[br0 + ko]);
      bf16x8 fb1 = __builtin_bit_cast(bf16x8, lds4[br1 + ko]);
      a00 = __builtin_amdgcn_mfma_f32_32x32x16_bf16(fa0, fb0, a00, 0, 0, 0);
      a01 = __builtin_amdgcn_mfma_f32_32x32x16_bf16(fa0, fb1, a01, 0, 0, 0);
      a10 = __builtin_amdgcn_mfma_f32_32x32x16_bf16(fa1, fb0, a10, 0, 0, 0);
      a11 = __builtin_amdgcn_mfma_f32_32x32x16_bf16(fa1, fb1, a11, 0, 0, 0);
    }

    // per-tile epilogue: for each of 64 rows, partial LSE over the 64 cols.
    // C/D layout: col = C + bc*32 + (lane&31),
    //             row = R + ar*32 + (reg&3) + 8*(reg>>2) + 4*(lane>>5)
#pragma unroll
    for (int ar = 0; ar < 2; ++ar) {
#pragma unroll
      for (int reg = 0; reg < 16; ++reg) {
        const int r = R + ar * 32 + (reg & 3) + 8 * (reg >> 2) + 4 * hi;
        const float p0 = (ar ? a10[reg] : a00[reg]) * 10.0f;
        const float p1 = (ar ? a11[reg] : a01[reg]) * 10.0f;
        float m = fmaxf(p0, p1);
#pragma unroll
        for (int d = 1; d < 32; d <<= 1) m = fmaxf(m, __shfl_xor(m, d));
        float s = __expf(p0 - m) + __expf(p1 - m);
#pragma unroll
        for (int d = 1; d < 32; d <<= 1) s += __shfl_xor(s, d);
        if (lo5 == 0) { mbuf[r][tc] = m; sbuf[r][tc] = s; }
        // target logit: row r, col r+1 (only rows 0..254)
        const int tcol = r + 1 - C;
        if (r < NT - 1 && tcol >= 0 && tcol < 64) {
          if (lo5 == (tcol & 31)) tbuf[r] = (tcol >= 32) ? p1 : p0;
        }
      }
    }
  }
  __syncthreads();

  // ---- phase 3: merge 4 col-groups per row, subtract target, block-reduce
  float val = 0.0f;
  if (t < NT - 1) {
    const float m0 = mbuf[t][0], m1 = mbuf[t][1], m2 = mbuf[t][2], m3 = mbuf[t][3];
    const float m = fmaxf(fmaxf(m0, m1), fmaxf(m2, m3));
    const float s = sbuf[t][0] * __expf(m0 - m) + sbuf[t][1] * __expf(m1 - m) +
                    sbuf[t][2] * __expf(m2 - m) + sbuf[t][3] * __expf(m3 - m);
    val = m + __logf(s) - tbuf[t];
  }
#pragma unroll
  for (int d = 1; d < 64; d <<= 1) val += __shfl_xor(val, d);
  if (lane == 0) redbuf[wave] = val;
  __syncthreads();
  if (t == 0) {
    float s = 0.f;
#pragma unroll
    for (int w = 0; w < 8; ++w) s += redbuf[w];
    partial[b] = s;
  }
}

// ---------------- K3: 512 partials -> mean (deterministic) ----------------
__global__ __launch_bounds__(256) void reduce_kernel(
    const float* __restrict__ partial, float* __restrict__ out) {
  const int t = threadIdx.x;
  float v = partial[t] + partial[t + 256];
#pragma unroll
  for (int d = 1; d < 64; d <<= 1) v += __shfl_xor(v, d);
  __shared__ float red[4];
  if ((t & 63) == 0) red[t >> 6] = v;
  __syncthreads();
  if (t == 0)
    out[0] = (red[0] + red[1] + red[2] + red[3]) * (1.0f / (float)(NB * (NT - 1)));
}

extern "C" void kernel_launch(void* const* d_in, const int* in_sizes, int n_in,
                              void* d_out, int out_size, void* d_ws, size_t ws_size,
                              hipStream_t stream) {
  (void)in_sizes; (void)n_in; (void)out_size; (void)ws_size;
  const float* x = (const float*)d_in[0];
  float* out = (float*)d_out;
  float* partial = (float*)d_ws;   // 2 KiB

  hipLaunchKernelGGL(fused_kernel, dim3(NB), dim3(512), 0, stream, x, partial);
  hipLaunchKernelGGL(reduce_kernel, dim3(1), dim3(256), 0, stream, partial, out);
}

// Round 3
// 87.640 us; speedup vs baseline: 2.1257x; 1.0354x over previous
//
#include <hip/hip_runtime.h>

// TemporalContrastiveLoss: B=512, T=256, D=256, temperature 0.1.
// K1: normalize rows (fp32) -> bf16 into ws (streaming, HBM-bound).
// K2: per-batch S=F*F^T via 64x64 wave-tiles of mfma_32x32x16_bf16 from
//     swizzled LDS (staged via global_load_lds w=16, inverse-swizzled src),
//     fused LSE with FIXED max=10 (diagonal), minus super-diagonal.
// K3: deterministic 512->1 reduction.

typedef float f32x4  __attribute__((ext_vector_type(4)));
typedef float f32x16 __attribute__((ext_vector_type(16)));
typedef unsigned int   u32x4 __attribute__((ext_vector_type(4)));
typedef unsigned short u16x4 __attribute__((ext_vector_type(4)));
typedef __bf16 bf16x8 __attribute__((ext_vector_type(8)));

#define NB   512
#define NT   256
#define ND   256

__device__ __forceinline__ unsigned int f2bf_rne(float f) {
  unsigned int u = __float_as_uint(f);
  return (u + 0x7fffu + ((u >> 16) & 1u)) >> 16;
}

// ---------------- K1: one wave per row: normalize + cast to bf16 ----------
__global__ __launch_bounds__(256) void norm_bf16_kernel(
    const float* __restrict__ x, unsigned short* __restrict__ fn) {
  const int wave = threadIdx.x >> 6;
  const int lane = threadIdx.x & 63;
  const long long row = (long long)blockIdx.x * 4 + wave;   // 131072 rows
  const f32x4* xr = (const f32x4*)(x + row * ND);
  f32x4 v = xr[lane];                                       // 16B/lane, coalesced
  float ss = v.x * v.x + v.y * v.y + v.z * v.z + v.w * v.w;
#pragma unroll
  for (int d = 1; d < 64; d <<= 1) ss += __shfl_xor(ss, d);
  const float inv = rsqrtf(fmaxf(ss, 1e-24f));              // eps=1e-12 on norm
  u16x4 o;
  o.x = (unsigned short)f2bf_rne(v.x * inv);
  o.y = (unsigned short)f2bf_rne(v.y * inv);
  o.z = (unsigned short)f2bf_rne(v.z * inv);
  o.w = (unsigned short)f2bf_rne(v.w * inv);
  ((u16x4*)(fn + row * ND))[lane] = o;                      // 8B/lane, coalesced
}

// ---------------- K2: per-batch GEMM + fused LSE --------------------------
// LDS matrix layout: [256 rows][32 chunks of 16B], chunk slot = c ^ (row&7)
// (byte ^= (row&7)<<4): breaks the 16-way bank conflict of stride-512B
// ds_read_b128 fragment reads. Staged with global_load_lds (linear LDS dest,
// inverse-swizzled per-lane GLOBAL source: src_chunk = p ^ ((p>>5)&7)).
__global__ __launch_bounds__(512, 2) void sim_lse_kernel(
    const unsigned short* __restrict__ fn, float* __restrict__ partial) {
  __shared__ u32x4 lds4[NT * 32];      // 128 KiB bf16 matrix
  __shared__ float sbuf[NT][4];        // per-row, per-64col-group sum exp(p-10)
  __shared__ float tbuf[NT];           // per-row target logit (x10 scale)
  __shared__ float redbuf[8];

  const int b    = blockIdx.x;
  const int t    = threadIdx.x;
  const int wave = t >> 6;
  const int lane = t & 63;

  // ---- stage F[b] (bf16) into swizzled LDS via global_load_lds w=16
  {
    const unsigned short* gb = fn + (size_t)b * (NT * ND);
#pragma unroll
    for (int i = 0; i < 16; ++i) {
      const int p   = (wave * 16 + i) * 64 + lane;    // linear 16B-chunk index
      const int src = p ^ ((p >> 5) & 7);             // inverse swizzle on source
      __builtin_amdgcn_global_load_lds(
          (const __attribute__((address_space(1))) unsigned int*)(gb + (size_t)src * 8),
          (__attribute__((address_space(3))) unsigned int*)(&lds4[(wave * 16 + i) * 64]),
          16, 0, 0);
    }
  }
  __syncthreads();   // drains vmcnt -> LDS tile ready

  // ---- GEMM 64x64 wave-tiles + per-tile partial sum-exp
  const int lo5 = lane & 31;
  const int hi  = lane >> 5;
  const int sx  = lo5 & 7;             // frag rows are base+lo5 -> row&7 = sx

  // chunk slot within a row for k-block kb, this lane: (kb*2|hi) ^ sx
  int kbo[16];
#pragma unroll
  for (int kb = 0; kb < 16; ++kb)
    kbo[kb] = ((kb * 2) ^ (sx & 6)) | (hi ^ (sx & 1));

#pragma unroll 1
  for (int ti = 0; ti < 2; ++ti) {
    const int tile = wave + ti * 8;     // 16 tiles: (tr,tc) in 4x4 grid
    const int tr = tile >> 2, tc = tile & 3;
    const int R = tr * 64, C = tc * 64;
    const int ar0 = (R + lo5) * 32, ar1 = (R + 32 + lo5) * 32;
    const int br0 = (C + lo5) * 32, br1 = (C + 32 + lo5) * 32;

    f32x16 a00, a01, a10, a11;
#pragma unroll
    for (int e = 0; e < 16; ++e) { a00[e] = 0.f; a01[e] = 0.f; a10[e] = 0.f; a11[e] = 0.f; }

#pragma unroll
    for (int kb = 0; kb < 16; ++kb) {
      const int ko = kbo[kb];
      bf16x8 fa0 = __builtin_bit_cast(bf16x8, lds4[ar0 + ko]);
      bf16x8 fa1 = __builtin_bit_cast(bf16x8, lds4[ar1 + ko]);
      bf16x8 fb0 = __builtin_bit_cast(bf16x8, lds4[br0 + ko]);
      bf16x8 fb1 = __builtin_bit_cast(bf16x8, lds4[br1 + ko]);
      a00 = __builtin_amdgcn_mfma_f32_32x32x16_bf16(fa0, fb0, a00, 0, 0, 0);
      a01 = __builtin_amdgcn_mfma_f32_32x32x16_bf16(fa0, fb1, a01, 0, 0, 0);
      a10 = __builtin_amdgcn_mfma_f32_32x32x16_bf16(fa1, fb0, a10, 0, 0, 0);
      a11 = __builtin_amdgcn_mfma_f32_32x32x16_bf16(fa1, fb1, a11, 0, 0, 0);
    }

    // per-tile epilogue: fixed max = 10 (diagonal: unit vectors, cos<=1).
    // C/D layout: col = C + bc*32 + (lane&31),
    //             row = R + ar*32 + (reg&3) + 8*(reg>>2) + 4*(lane>>5)
#pragma unroll
    for (int ar = 0; ar < 2; ++ar) {
#pragma unroll
      for (int reg = 0; reg < 16; ++reg) {
        const int r = R + ar * 32 + (reg & 3) + 8 * (reg >> 2) + 4 * hi;
        const float p0 = (ar ? a10[reg] : a00[reg]) * 10.0f;
        const float p1 = (ar ? a11[reg] : a01[reg]) * 10.0f;
        float s = __expf(p0 - 10.0f) + __expf(p1 - 10.0f);
#pragma unroll
        for (int d = 1; d < 32; d <<= 1) s += __shfl_xor(s, d);
        if (lo5 == 0) sbuf[r][tc] = s;
        // target logit: row r, col r+1 (only rows 0..254)
        const int tcol = r + 1 - C;
        if (r < NT - 1 && tcol >= 0 && tcol < 64) {
          if (lo5 == (tcol & 31)) tbuf[r] = (tcol >= 32) ? p1 : p0;
        }
      }
    }
  }
  __syncthreads();

  // ---- merge 4 col-groups per row, subtract target, block-reduce
  float val = 0.0f;
  if (t < NT - 1) {
    const float s = sbuf[t][0] + sbuf[t][1] + sbuf[t][2] + sbuf[t][3];
    val = 10.0f + __logf(s) - tbuf[t];
  }
#pragma unroll
  for (int d = 1; d < 64; d <<= 1) val += __shfl_xor(val, d);
  if (lane == 0) redbuf[wave] = val;
  __syncthreads();
  if (t == 0) {
    float s = 0.f;
#pragma unroll
    for (int w = 0; w < 8; ++w) s += redbuf[w];
    partial[b] = s;
  }
}

// ---------------- K3: 512 partials -> mean (deterministic) ----------------
__global__ __launch_bounds__(256) void reduce_kernel(
    const float* __restrict__ partial, float* __restrict__ out) {
  const int t = threadIdx.x;
  float v = partial[t] + partial[t + 256];
#pragma unroll
  for (int d = 1; d < 64; d <<= 1) v += __shfl_xor(v, d);
  __shared__ float red[4];
  if ((t & 63) == 0) red[t >> 6] = v;
  __syncthreads();
  if (t == 0)
    out[0] = (red[0] + red[1] + red[2] + red[3]) * (1.0f / (float)(NB * (NT - 1)));
}

extern "C" void kernel_launch(void* const* d_in, const int* in_sizes, int n_in,
                              void* d_out, int out_size, void* d_ws, size_t ws_size,
                              hipStream_t stream) {
  (void)in_sizes; (void)n_in; (void)out_size; (void)ws_size;
  const float* x = (const float*)d_in[0];
  float* out = (float*)d_out;
  unsigned short* fn = (unsigned short*)d_ws;                        // 64 MiB bf16
  float* partial = (float*)((char*)d_ws + (size_t)NB * NT * ND * 2); // +2 KiB

  hipLaunchKernelGGL(norm_bf16_kernel, dim3((NB * NT) / 4), dim3(256), 0, stream,
                     x, fn);
  hipLaunchKernelGGL(sim_lse_kernel, dim3(NB), dim3(512), 0, stream, fn, partial);
  hipLaunchKernelGGL(reduce_kernel, dim3(1), dim3(256), 0, stream, partial, out);
}

// Round 4
// 67.648 us; speedup vs baseline: 2.7539x; 1.2955x over previous
//
#include <hip/hip_runtime.h>

// TemporalContrastiveLoss: B=512, T=256, D=256, temperature 0.1.
// K1: normalize rows (fp32) -> bf16 into ws (streaming, HBM-bound).
// K2: per-batch S=F*F^T via 64x64 wave-tiles of mfma_32x32x16_bf16 from
//     swizzled LDS (staged via global_load_lds w=16, inverse-swizzled src).
//     LSE via SYMMETRY: row-sum == column-sum -> per-lane register-local
//     exp-accumulation (one shfl + one LDS write per 32-col group).
//     Fixed max = 10 (diagonal, unit vectors). Minus super-diagonal target.
// K3: deterministic 512->1 reduction.

typedef float f32x4  __attribute__((ext_vector_type(4)));
typedef float f32x16 __attribute__((ext_vector_type(16)));
typedef unsigned int   u32x4 __attribute__((ext_vector_type(4)));
typedef unsigned short u16x4 __attribute__((ext_vector_type(4)));
typedef __bf16 bf16x8 __attribute__((ext_vector_type(8)));

#define NB   512
#define NT   256
#define ND   256

#define K10L2E 14.42695041f   // 10 * log2(e)

__device__ __forceinline__ unsigned int f2bf_rne(float f) {
  unsigned int u = __float_as_uint(f);
  return (u + 0x7fffu + ((u >> 16) & 1u)) >> 16;
}

// ---------------- K1: one wave per row: normalize + cast to bf16 ----------
__global__ __launch_bounds__(256) void norm_bf16_kernel(
    const float* __restrict__ x, unsigned short* __restrict__ fn) {
  const int wave = threadIdx.x >> 6;
  const int lane = threadIdx.x & 63;
  const long long row = (long long)blockIdx.x * 4 + wave;   // 131072 rows
  const f32x4* xr = (const f32x4*)(x + row * ND);
  f32x4 v = xr[lane];                                       // 16B/lane, coalesced
  float ss = v.x * v.x + v.y * v.y + v.z * v.z + v.w * v.w;
#pragma unroll
  for (int d = 1; d < 64; d <<= 1) ss += __shfl_xor(ss, d);
  const float inv = rsqrtf(fmaxf(ss, 1e-24f));              // eps=1e-12 on norm
  u16x4 o;
  o.x = (unsigned short)f2bf_rne(v.x * inv);
  o.y = (unsigned short)f2bf_rne(v.y * inv);
  o.z = (unsigned short)f2bf_rne(v.z * inv);
  o.w = (unsigned short)f2bf_rne(v.w * inv);
  ((u16x4*)(fn + row * ND))[lane] = o;                      // 8B/lane, coalesced
}

// ---------------- K2: per-batch GEMM + fused LSE --------------------------
// LDS matrix layout: [256 rows][32 chunks of 16B], chunk slot = c ^ (row&7)
// (byte ^= (row&7)<<4): breaks the 16-way bank conflict of stride-512B
// ds_read_b128 fragment reads. Staged with global_load_lds (linear LDS dest,
// inverse-swizzled per-lane GLOBAL source: src_chunk = p ^ ((p>>5)&7)).
__global__ __launch_bounds__(512, 2) void sim_lse_kernel(
    const unsigned short* __restrict__ fn, float* __restrict__ partial) {
  __shared__ u32x4 lds4[NT * 32];      // 128 KiB bf16 matrix
  __shared__ float sbuf[NT][5];        // per-col, per-64row-group sum exp(p-10); pad->stride 5 (coprime 32)
  __shared__ float tbuf[NT];           // per-row target logit (x10 scale)
  __shared__ float redbuf[8];

  const int b    = blockIdx.x;
  const int t    = threadIdx.x;
  const int wave = t >> 6;
  const int lane = t & 63;

  // ---- stage F[b] (bf16) into swizzled LDS via global_load_lds w=16
  {
    const unsigned short* gb = fn + (size_t)b * (NT * ND);
#pragma unroll
    for (int i = 0; i < 16; ++i) {
      const int p   = (wave * 16 + i) * 64 + lane;    // linear 16B-chunk index
      const int src = p ^ ((p >> 5) & 7);             // inverse swizzle on source
      __builtin_amdgcn_global_load_lds(
          (const __attribute__((address_space(1))) unsigned int*)(gb + (size_t)src * 8),
          (__attribute__((address_space(3))) unsigned int*)(&lds4[(wave * 16 + i) * 64]),
          16, 0, 0);
    }
  }
  __syncthreads();   // drains vmcnt -> LDS tile ready

  // ---- GEMM 64x64 wave-tiles + register-local column-sum epilogue
  const int lo5 = lane & 31;
  const int hi  = lane >> 5;
  const int sx  = lo5 & 7;             // frag rows are base+lo5 -> row&7 = sx

  // chunk slot within a row for k-block kb, this lane: (kb*2|hi) ^ sx
  int kbo[16];
#pragma unroll
  for (int kb = 0; kb < 16; ++kb)
    kbo[kb] = ((kb * 2) ^ (sx & 6)) | (hi ^ (sx & 1));

#pragma unroll 1
  for (int ti = 0; ti < 2; ++ti) {
    const int tile = wave + ti * 8;     // 16 tiles: (tr,tc) in 4x4 grid
    const int tr = tile >> 2, tc = tile & 3;
    const int R = tr * 64, C = tc * 64;
    const int ar0 = (R + lo5) * 32, ar1 = (R + 32 + lo5) * 32;
    const int br0 = (C + lo5) * 32, br1 = (C + 32 + lo5) * 32;

    f32x16 a00, a01, a10, a11;
#pragma unroll
    for (int e = 0; e < 16; ++e) { a00[e] = 0.f; a01[e] = 0.f; a10[e] = 0.f; a11[e] = 0.f; }

#pragma unroll
    for (int kb = 0; kb < 16; ++kb) {
      const int ko = kbo[kb];
      bf16x8 fa0 = __builtin_bit_cast(bf16x8, lds4[ar0 + ko]);
      bf16x8 fa1 = __builtin_bit_cast(bf16x8, lds4[ar1 + ko]);
      bf16x8 fb0 = __builtin_bit_cast(bf16x8, lds4[br0 + ko]);
      bf16x8 fb1 = __builtin_bit_cast(bf16x8, lds4[br1 + ko]);
      a00 = __builtin_amdgcn_mfma_f32_32x32x16_bf16(fa0, fb0, a00, 0, 0, 0);
      a01 = __builtin_amdgcn_mfma_f32_32x32x16_bf16(fa0, fb1, a01, 0, 0, 0);
      a10 = __builtin_amdgcn_mfma_f32_32x32x16_bf16(fa1, fb0, a10, 0, 0, 0);
      a11 = __builtin_amdgcn_mfma_f32_32x32x16_bf16(fa1, fb1, a11, 0, 0, 0);
    }

    // Column-sum epilogue (S symmetric: row-LSE sum == column sum).
    // C/D layout: col = C + bc*32 + (lane&31),
    //             row = R + ar*32 + (reg&3) + 8*(reg>>2) + 4*(lane>>5)
    // Lane (lo5,hi) owns col C+bc*32+lo5; its 16 regs cover 16 of 32 rows,
    // the hi^1 partner covers the other 16 -> one shfl_xor(32) completes
    // rows R..R+63 for the column.
    float e0 = 0.f, e1 = 0.f;
#pragma unroll
    for (int reg = 0; reg < 16; ++reg) {
      e0 += exp2f(fmaf(a00[reg], K10L2E, -K10L2E));
      e0 += exp2f(fmaf(a10[reg], K10L2E, -K10L2E));
      e1 += exp2f(fmaf(a01[reg], K10L2E, -K10L2E));
      e1 += exp2f(fmaf(a11[reg], K10L2E, -K10L2E));
    }
    e0 += __shfl_xor(e0, 32);
    e1 += __shfl_xor(e1, 32);
    if (hi == 0) sbuf[C + lo5][tr]      = e0;   // stride-5 floats: conflict-free
    else         sbuf[C + 32 + lo5][tr] = e1;

    // target logit: row r, col r+1 (rows 0..254), read from acc regs
#pragma unroll
    for (int ar = 0; ar < 2; ++ar) {
#pragma unroll
      for (int reg = 0; reg < 16; ++reg) {
        const int r = R + ar * 32 + (reg & 3) + 8 * (reg >> 2) + 4 * hi;
        const int tcol = r + 1 - C;
        if (r < NT - 1 && tcol >= 0 && tcol < 64 && lo5 == (tcol & 31)) {
          const float v = (tcol < 32) ? (ar ? a10[reg] : a00[reg])
                                      : (ar ? a11[reg] : a01[reg]);
          tbuf[r] = 10.0f * v;
        }
      }
    }
  }
  __syncthreads();

  // ---- merge 4 row-groups per column, subtract target, block-reduce
  float val = 0.0f;
  if (t < NT - 1) {
    const float s = sbuf[t][0] + sbuf[t][1] + sbuf[t][2] + sbuf[t][3];
    val = 10.0f + __logf(s) - tbuf[t];
  }
#pragma unroll
  for (int d = 1; d < 64; d <<= 1) val += __shfl_xor(val, d);
  if (lane == 0) redbuf[wave] = val;
  __syncthreads();
  if (t == 0) {
    float s = 0.f;
#pragma unroll
    for (int w = 0; w < 8; ++w) s += redbuf[w];
    partial[b] = s;
  }
}

// ---------------- K3: 512 partials -> mean (deterministic) ----------------
__global__ __launch_bounds__(256) void reduce_kernel(
    const float* __restrict__ partial, float* __restrict__ out) {
  const int t = threadIdx.x;
  float v = partial[t] + partial[t + 256];
#pragma unroll
  for (int d = 1; d < 64; d <<= 1) v += __shfl_xor(v, d);
  __shared__ float red[4];
  if ((t & 63) == 0) red[t >> 6] = v;
  __syncthreads();
  if (t == 0)
    out[0] = (red[0] + red[1] + red[2] + red[3]) * (1.0f / (float)(NB * (NT - 1)));
}

extern "C" void kernel_launch(void* const* d_in, const int* in_sizes, int n_in,
                              void* d_out, int out_size, void* d_ws, size_t ws_size,
                              hipStream_t stream) {
  (void)in_sizes; (void)n_in; (void)out_size; (void)ws_size;
  const float* x = (const float*)d_in[0];
  float* out = (float*)d_out;
  unsigned short* fn = (unsigned short*)d_ws;                        // 64 MiB bf16
  float* partial = (float*)((char*)d_ws + (size_t)NB * NT * ND * 2); // +2 KiB

  hipLaunchKernelGGL(norm_bf16_kernel, dim3((NB * NT) / 4), dim3(256), 0, stream,
                     x, fn);
  hipLaunchKernelGGL(sim_lse_kernel, dim3(NB), dim3(512), 0, stream, fn, partial);
  hipLaunchKernelGGL(reduce_kernel, dim3(1), dim3(256), 0, stream, partial, out);
}

// Round 5
// 50.226 us; speedup vs baseline: 3.7091x; 1.3469x over previous
//
#include <hip/hip_runtime.h>

// TemporalContrastiveLoss: B=512, T=256, D=256, temperature 0.1.
// Single fused kernel per batch (512 thr, 1 block/CU):
//  phase 1: streaming fp32 -> bf16 (RNE) cast of RAW x into swizzled LDS
//           (no norms -- pure elementwise, HBM-bound, fully pipelined).
//  phase 2: S_raw = X*X^T via 64x64 wave-tiles of mfma_32x32x16_bf16.
//           Diagonal-first tile schedule: round 0 computes the 4 diagonal
//           tiles, whose diag regs give inv[r] = rsqrt(S_raw[r][r]) -> LDS.
//           Epilogue scales by inv_row*inv_col (cos), fixed max = 10
//           (diag==1 exactly by construction), symmetric column-sum LSE
//           (register-local, one shfl per 32-col group), super-diag target.
// K3: deterministic 512->1 reduction -> mean.

typedef float f32x4  __attribute__((ext_vector_type(4)));
typedef float f32x16 __attribute__((ext_vector_type(16)));
typedef unsigned int   u32x2 __attribute__((ext_vector_type(2)));
typedef unsigned int   u32x4 __attribute__((ext_vector_type(4)));
typedef __bf16 bf16x8 __attribute__((ext_vector_type(8)));

#define NB   512
#define NT   256
#define ND   256

#define K10L2E 14.42695041f   // 10 * log2(e)

__device__ __forceinline__ unsigned int f2bf_rne(float f) {
  unsigned int u = __float_as_uint(f);
  return (u + 0x7fffu + ((u >> 16) & 1u)) >> 16;
}

// LDS matrix layout: [256 rows][32 chunks of 16B], chunk slot = c ^ (row&7)
// (byte ^= (row&7)<<4): breaks the 16-way bank conflict of stride-512B
// ds_read_b128 fragment reads.
__global__ __launch_bounds__(512, 2) void fused_kernel(
    const float* __restrict__ x, float* __restrict__ partial) {
  __shared__ u32x4 lds4[NT * 32];      // 128 KiB bf16 raw matrix (swizzled)
  __shared__ float invbuf[NT];         // 1/||x_r|| from MFMA diagonal
  __shared__ float sbuf[NT][5];        // per-col, per-64row-group sum exp(p-10)
  __shared__ float tbuf[NT];           // per-row target logit (x10, normalized)
  __shared__ float redbuf[8];

  const int b    = blockIdx.x;
  const int t    = threadIdx.x;
  const int wave = t >> 6;
  const int lane = t & 63;

  // ---- phase 1: elementwise cast fp32 -> bf16, swizzled LDS store --------
  {
    const f32x4* xb = (const f32x4*)(x + (size_t)b * (NT * ND));
    unsigned int* l32 = (unsigned int*)lds4;
#pragma unroll 8
    for (int i = 0; i < 32; ++i) {
      const int r = wave * 32 + i;
      f32x4 v = xb[r * 64 + lane];                    // 16B/lane, coalesced
      u32x2 o;
      o.x = f2bf_rne(v.x) | (f2bf_rne(v.y) << 16);
      o.y = f2bf_rne(v.z) | (f2bf_rne(v.w) << 16);
      const int slot = (lane >> 1) ^ (r & 7);         // 16B chunk = lane>>1
      *(u32x2*)&l32[r * 128 + slot * 4 + (lane & 1) * 2] = o;
    }
  }
  __syncthreads();

  // ---- phase 2: GEMM 64x64 wave-tiles, diag-first, fused epilogue --------
  const int lo5 = lane & 31;
  const int hi  = lane >> 5;
  const int sx  = lo5 & 7;             // frag rows are base+lo5 -> row&7 = sx
  const int hx  = hi ^ (sx & 1);
  const int sx6 = sx & 6;

#pragma unroll 1
  for (int ti = 0; ti < 2; ++ti) {
    // diag-first schedule: round0 w<4 -> (w,w); w>=4 -> (w-4, w-4+1);
    //                      round1 -> +2, +3 diagonals. All 16 covered.
    const int tr = wave & 3;
    const int tc = (tr + (wave >> 2) + ti * 2) & 3;
    const int R = tr * 64, C = tc * 64;
    const int ar0 = (R + lo5) * 32, ar1 = (R + 32 + lo5) * 32;
    const int br0 = (C + lo5) * 32, br1 = (C + 32 + lo5) * 32;

    f32x16 a00, a01, a10, a11;
#pragma unroll
    for (int e = 0; e < 16; ++e) { a00[e] = 0.f; a01[e] = 0.f; a10[e] = 0.f; a11[e] = 0.f; }

#pragma unroll
    for (int kb = 0; kb < 16; ++kb) {
      const int ko = ((kb * 2) ^ sx6) | hx;           // swizzled chunk slot
      bf16x8 fa0 = __builtin_bit_cast(bf16x8, lds4[ar0 + ko]);
      bf16x8 fa1 = __builtin_bit_cast(bf16x8, lds4[ar1 + ko]);
      bf16x8 fb0 = __builtin_bit_cast(bf16x8, lds4[br0 + ko]);
      bf16x8 fb1 = __builtin_bit_cast(bf16x8, lds4[br1 + ko]);
      a00 = __builtin_amdgcn_mfma_f32_32x32x16_bf16(fa0, fb0, a00, 0, 0, 0);
      a01 = __builtin_amdgcn_mfma_f32_32x32x16_bf16(fa0, fb1, a01, 0, 0, 0);
      a10 = __builtin_amdgcn_mfma_f32_32x32x16_bf16(fa1, fb0, a10, 0, 0, 0);
      a11 = __builtin_amdgcn_mfma_f32_32x32x16_bf16(fa1, fb1, a11, 0, 0, 0);
    }

    // round 0: diagonal tiles publish inv[r] = rsqrt(S_raw[r][r])
    if (ti == 0) {
      if ((wave >> 2) == 0) {                         // tr == tc
        float dv0 = 1.0f, dv1 = 1.0f;
#pragma unroll
        for (int rg = 0; rg < 16; ++rg) {
          const int rowe = (rg & 3) + 8 * (rg >> 2) + 4 * hi;
          if (rowe == lo5) { dv0 = a00[rg]; dv1 = a11[rg]; }
        }
        if (hi == ((lo5 >> 2) & 1)) {                 // lane holding diag col
          invbuf[C + lo5]      = rsqrtf(fmaxf(dv0, 1e-24f));
          invbuf[C + 32 + lo5] = rsqrtf(fmaxf(dv1, 1e-24f));
        }
      }
      __syncthreads();                                // inv[256] now valid
    }

    // Column-sum epilogue (S symmetric: row-LSE sum == column sum).
    // C/D layout: col = C + bc*32 + (lane&31),
    //             row = R + ar*32 + (reg&3) + 8*(reg>>2) + 4*(lane>>5)
    const float icl0 = invbuf[C + lo5] * K10L2E;
    const float icl1 = invbuf[C + 32 + lo5] * K10L2E;
    float e0 = 0.f, e1 = 0.f;
#pragma unroll
    for (int rg = 0; rg < 16; ++rg) {
      const int rowe = (rg & 3) + 8 * (rg >> 2) + 4 * hi;
      const float ir0 = invbuf[R + rowe];             // rows R..R+31
      const float ir1 = invbuf[R + 32 + rowe];        // rows R+32..R+63
      e0 += exp2f(fmaf(a00[rg] * ir0, icl0, -K10L2E));
      e0 += exp2f(fmaf(a10[rg] * ir1, icl0, -K10L2E));
      e1 += exp2f(fmaf(a01[rg] * ir0, icl1, -K10L2E));
      e1 += exp2f(fmaf(a11[rg] * ir1, icl1, -K10L2E));
    }
    e0 += __shfl_xor(e0, 32);
    e1 += __shfl_xor(e1, 32);
    if (hi == 0) sbuf[C + lo5][tr]      = e0;   // stride-5: conflict-free
    else         sbuf[C + 32 + lo5][tr] = e1;

    // target logit: row r, col r+1 (rows 0..254), normalized, x10
#pragma unroll
    for (int ar = 0; ar < 2; ++ar) {
#pragma unroll
      for (int rg = 0; rg < 16; ++rg) {
        const int r = R + ar * 32 + (rg & 3) + 8 * (rg >> 2) + 4 * hi;
        const int tcol = r + 1 - C;
        if (r < NT - 1 && tcol >= 0 && tcol < 64 && lo5 == (tcol & 31)) {
          const float v = (tcol < 32) ? (ar ? a10[rg] : a00[rg])
                                      : (ar ? a11[rg] : a01[rg]);
          tbuf[r] = 10.0f * v * invbuf[r] * invbuf[r + 1];
        }
      }
    }
  }
  __syncthreads();

  // ---- merge 4 row-groups per column, subtract target, block-reduce ------
  float val = 0.0f;
  if (t < NT - 1) {
    const float s = sbuf[t][0] + sbuf[t][1] + sbuf[t][2] + sbuf[t][3];
    val = 10.0f + __logf(s) - tbuf[t];
  }
#pragma unroll
  for (int d = 1; d < 64; d <<= 1) val += __shfl_xor(val, d);
  if (lane == 0) redbuf[wave] = val;
  __syncthreads();
  if (t == 0) {
    float s = 0.f;
#pragma unroll
    for (int w = 0; w < 8; ++w) s += redbuf[w];
    partial[b] = s;
  }
}

// ---------------- K3: 512 partials -> mean (deterministic) ----------------
__global__ __launch_bounds__(256) void reduce_kernel(
    const float* __restrict__ partial, float* __restrict__ out) {
  const int t = threadIdx.x;
  float v = partial[t] + partial[t + 256];
#pragma unroll
  for (int d = 1; d < 64; d <<= 1) v += __shfl_xor(v, d);
  __shared__ float red[4];
  if ((t & 63) == 0) red[t >> 6] = v;
  __syncthreads();
  if (t == 0)
    out[0] = (red[0] + red[1] + red[2] + red[3]) * (1.0f / (float)(NB * (NT - 1)));
}

extern "C" void kernel_launch(void* const* d_in, const int* in_sizes, int n_in,
                              void* d_out, int out_size, void* d_ws, size_t ws_size,
                              hipStream_t stream) {
  (void)in_sizes; (void)n_in; (void)out_size; (void)ws_size;
  const float* x = (const float*)d_in[0];
  float* out = (float*)d_out;
  float* partial = (float*)d_ws;   // 2 KiB

  hipLaunchKernelGGL(fused_kernel, dim3(NB), dim3(512), 0, stream, x, partial);
  hipLaunchKernelGGL(reduce_kernel, dim3(1), dim3(256), 0, stream, partial, out);
}

// Round 6
// 39.204 us; speedup vs baseline: 4.7519x; 1.2811x over previous
//
#include <hip/hip_runtime.h>

// TemporalContrastiveLoss: B=512, T=256, D=256, temperature 0.1.
// Grid = 256 blocks (1/CU), each block does 2 batches sequentially.
// Per batch: S_raw = X*X^T accumulated over 4 K-chunks (64 cols each).
// K-chunk pipeline (double-buffered 32 KB LDS chunk):
//   iter g: {vmwait; cast fp32->bf16; swizzled LDS write chunk g} ;
//           {issue global loads chunk g+1} ; barrier ; {MFMA chunk g}.
// Epilogue per batch (g=3,7): inv=rsqrt(diag) from diagonal tiles,
// scaled exp column-sums (symmetric row==col sum), fixed max=10,
// super-diagonal target, per-batch partial. K3: 512->1 mean.

typedef float f32x4  __attribute__((ext_vector_type(4)));
typedef float f32x16 __attribute__((ext_vector_type(16)));
typedef unsigned int u32x2 __attribute__((ext_vector_type(2)));
typedef unsigned int u32x4 __attribute__((ext_vector_type(4)));
typedef __bf16 bf16x8 __attribute__((ext_vector_type(8)));

#define NB 512
#define NT 256
#define ND 256
#define K10L2E 14.42695041f   // 10 * log2(e)

#define MFMA32 __builtin_amdgcn_mfma_f32_32x32x16_bf16

__device__ __forceinline__ unsigned int f2bf_rne(float f) {
  unsigned int u = __float_as_uint(f);
  return (u + 0x7fffu + ((u >> 16) & 1u)) >> 16;
}

// LDS chunk layout: [256 rows][8 slots of 16B], slot = c ^ (row&7)
// (byte ^= (row&7)<<4): spreads the stride-128B column reads across banks.
__global__ __launch_bounds__(512, 2) void fused_kernel(
    const float* __restrict__ x, float* __restrict__ partial) {
  __shared__ u32x4 ck[2 * NT * 8];   // 2 x 32 KiB K-chunk double buffer
  __shared__ float invbuf[NT];       // 1/||x_r|| from MFMA diagonal
  __shared__ float sbuf[NT][5];      // per-col, per-64row-group sum exp(p-10)
  __shared__ float tbuf[NT];         // per-row target logit (x10, normalized)
  __shared__ float redbuf[8];

  const int t    = threadIdx.x;
  const int wave = t >> 6;
  const int lane = t & 63;
  const int lo5  = lane & 31;
  const int hi   = lane >> 5;
  const int sx6  = lo5 & 6;          // (lo5&7)&6
  const int hx   = hi ^ (lo5 & 1);

  // tile assignment: wave w -> tiles (tr, tcA), (tr, tcB); w<4 has diag in A
  const int d   = wave >> 2;
  const int tr  = wave & 3;
  const int tcA = (tr + d) & 3;
  const int tcB = (tr + d + 2) & 3;
  const int R  = tr * 64, CA = tcA * 64, CB = tcB * 64;

  // staging assignment: wave covers rows wave*32..+31, 64 cols per chunk
  const int lrow = lane >> 4;        // 0..3
  const int lcol = lane & 15;        // f32x4 index within 64-col chunk
  const int srow = wave * 32;
  const size_t bstride = (size_t)NT * ND;

  f32x16 aA0, aA1, aA2, aA3, aB0, aB1, aB2, aB3;
#pragma unroll
  for (int e = 0; e < 16; ++e) {
    aA0[e] = 0.f; aA1[e] = 0.f; aA2[e] = 0.f; aA3[e] = 0.f;
    aB0[e] = 0.f; aB1[e] = 0.f; aB2[e] = 0.f; aB3[e] = 0.f;
  }

  f32x4 ld[8];
  {  // prologue: issue chunk g=0 loads (batch blockIdx.x, cols 0..63)
    const float* xb = x + (size_t)blockIdx.x * bstride;
#pragma unroll
    for (int i = 0; i < 8; ++i)
      ld[i] = *(const f32x4*)(xb + (srow + i * 4 + lrow) * ND + lcol * 4);
  }

#pragma unroll 1
  for (int g = 0; g < 8; ++g) {
    u32x4* ckb = &ck[(g & 1) * (NT * 8)];

    // (A) cast + swizzled LDS write of chunk g
#pragma unroll
    for (int i = 0; i < 8; ++i) {
      const int row = srow + i * 4 + lrow;
      u32x2 o;
      o.x = f2bf_rne(ld[i].x) | (f2bf_rne(ld[i].y) << 16);
      o.y = f2bf_rne(ld[i].z) | (f2bf_rne(ld[i].w) << 16);
      const int slot = (lcol >> 1) ^ (row & 7);
      *(u32x2*)((unsigned int*)(ckb + row * 8 + slot) + (lcol & 1) * 2) = o;
    }

    // (B) issue loads for chunk g+1 (in flight across compute)
    if (g < 7) {
      const int gn = g + 1;
      const float* xb = x + ((size_t)blockIdx.x + (size_t)(gn >> 2) * 256) * bstride;
      const int kc = (gn & 3) * 64;
#pragma unroll
      for (int i = 0; i < 8; ++i)
        ld[i] = *(const f32x4*)(xb + (srow + i * 4 + lrow) * ND + kc + lcol * 4);
    }

    // (C) chunk g complete for all waves
    __syncthreads();

    // (D) MFMA-accumulate chunk g: 4 k-blocks, shared A-frags, 2 tiles
#pragma unroll
    for (int kb = 0; kb < 4; ++kb) {
      const int ko = ((kb * 2) ^ sx6) | hx;   // swizzled slot
      bf16x8 fa0  = __builtin_bit_cast(bf16x8, ckb[(R + lo5) * 8 + ko]);
      bf16x8 fa1  = __builtin_bit_cast(bf16x8, ckb[(R + 32 + lo5) * 8 + ko]);
      bf16x8 fbA0 = __builtin_bit_cast(bf16x8, ckb[(CA + lo5) * 8 + ko]);
      bf16x8 fbA1 = __builtin_bit_cast(bf16x8, ckb[(CA + 32 + lo5) * 8 + ko]);
      bf16x8 fbB0 = __builtin_bit_cast(bf16x8, ckb[(CB + lo5) * 8 + ko]);
      bf16x8 fbB1 = __builtin_bit_cast(bf16x8, ckb[(CB + 32 + lo5) * 8 + ko]);
      aA0 = MFMA32(fa0, fbA0, aA0, 0, 0, 0);
      aA1 = MFMA32(fa0, fbA1, aA1, 0, 0, 0);
      aA2 = MFMA32(fa1, fbA0, aA2, 0, 0, 0);
      aA3 = MFMA32(fa1, fbA1, aA3, 0, 0, 0);
      aB0 = MFMA32(fa0, fbB0, aB0, 0, 0, 0);
      aB1 = MFMA32(fa0, fbB1, aB1, 0, 0, 0);
      aB2 = MFMA32(fa1, fbB0, aB2, 0, 0, 0);
      aB3 = MFMA32(fa1, fbB1, aB3, 0, 0, 0);
    }

    // ---- batch epilogue at g=3 (batch b) and g=7 (batch b+256) ----------
    if ((g & 3) == 3) {
      const int bb = (int)blockIdx.x + (g >> 2) * 256;

      // diagonal tiles (waves 0-3, tile A): publish inv = rsqrt(diag)
      if (d == 0) {
        float dv0 = 1.0f, dv1 = 1.0f;
#pragma unroll
        for (int rg = 0; rg < 16; ++rg) {
          const int rowe = (rg & 3) + 8 * (rg >> 2) + 4 * hi;
          if (rowe == lo5) { dv0 = aA0[rg]; dv1 = aA3[rg]; }
        }
        if (hi == ((lo5 >> 2) & 1)) {
          invbuf[R + lo5]      = rsqrtf(fmaxf(dv0, 1e-24f));
          invbuf[R + 32 + lo5] = rsqrtf(fmaxf(dv1, 1e-24f));
        }
      }
      __syncthreads();   // invbuf[256] valid

      // scaled exp column-sums, tile A (cols CA); row==col sum by symmetry
      {
        const float ic0 = invbuf[CA + lo5] * K10L2E;
        const float ic1 = invbuf[CA + 32 + lo5] * K10L2E;
        float e0 = 0.f, e1 = 0.f;
#pragma unroll
        for (int rg = 0; rg < 16; ++rg) {
          const int rowe = (rg & 3) + 8 * (rg >> 2) + 4 * hi;
          const float ir0 = invbuf[R + rowe], ir1 = invbuf[R + 32 + rowe];
          e0 += exp2f(fmaf(aA0[rg] * ir0, ic0, -K10L2E));
          e0 += exp2f(fmaf(aA2[rg] * ir1, ic0, -K10L2E));
          e1 += exp2f(fmaf(aA1[rg] * ir0, ic1, -K10L2E));
          e1 += exp2f(fmaf(aA3[rg] * ir1, ic1, -K10L2E));
        }
        e0 += __shfl_xor(e0, 32);
        e1 += __shfl_xor(e1, 32);
        if (hi == 0) sbuf[CA + lo5][tr] = e0;
        else         sbuf[CA + 32 + lo5][tr] = e1;
      }
      // tile B (cols CB)
      {
        const float ic0 = invbuf[CB + lo5] * K10L2E;
        const float ic1 = invbuf[CB + 32 + lo5] * K10L2E;
        float e0 = 0.f, e1 = 0.f;
#pragma unroll
        for (int rg = 0; rg < 16; ++rg) {
          const int rowe = (rg & 3) + 8 * (rg >> 2) + 4 * hi;
          const float ir0 = invbuf[R + rowe], ir1 = invbuf[R + 32 + rowe];
          e0 += exp2f(fmaf(aB0[rg] * ir0, ic0, -K10L2E));
          e0 += exp2f(fmaf(aB2[rg] * ir1, ic0, -K10L2E));
          e1 += exp2f(fmaf(aB1[rg] * ir0, ic1, -K10L2E));
          e1 += exp2f(fmaf(aB3[rg] * ir1, ic1, -K10L2E));
        }
        e0 += __shfl_xor(e0, 32);
        e1 += __shfl_xor(e1, 32);
        if (hi == 0) sbuf[CB + lo5][tr] = e0;
        else         sbuf[CB + 32 + lo5][tr] = e1;
      }

      // super-diagonal target (only tiles with tr==tcA or tcA==tr+1)
      if (tcA == tr || tcA == tr + 1) {
#pragma unroll
        for (int ar = 0; ar < 2; ++ar) {
#pragma unroll
          for (int rg = 0; rg < 16; ++rg) {
            const int r = R + ar * 32 + (rg & 3) + 8 * (rg >> 2) + 4 * hi;
            const int tcol = r + 1 - CA;
            if (r < NT - 1 && tcol >= 0 && tcol < 64 && lo5 == (tcol & 31)) {
              const float v = (tcol < 32) ? (ar ? aA2[rg] : aA0[rg])
                                          : (ar ? aA3[rg] : aA1[rg]);
              tbuf[r] = 10.0f * v * invbuf[r] * invbuf[r + 1];
            }
          }
        }
      }
      __syncthreads();   // sbuf/tbuf complete

      // merge 4 row-groups per column, subtract target, block-reduce
      float val = 0.0f;
      if (t < NT - 1) {
        const float s = sbuf[t][0] + sbuf[t][1] + sbuf[t][2] + sbuf[t][3];
        val = 10.0f + __logf(s) - tbuf[t];
      }
#pragma unroll
      for (int dd = 1; dd < 64; dd <<= 1) val += __shfl_xor(val, dd);
      if (lane == 0) redbuf[wave] = val;
      __syncthreads();
      if (t == 0) {
        float s = 0.f;
#pragma unroll
        for (int w = 0; w < 8; ++w) s += redbuf[w];
        partial[bb] = s;
      }

      // reset accumulators for next batch
#pragma unroll
      for (int e = 0; e < 16; ++e) {
        aA0[e] = 0.f; aA1[e] = 0.f; aA2[e] = 0.f; aA3[e] = 0.f;
        aB0[e] = 0.f; aB1[e] = 0.f; aB2[e] = 0.f; aB3[e] = 0.f;
      }
    }
  }
}

// ---------------- K3: 512 partials -> mean (deterministic) ----------------
__global__ __launch_bounds__(256) void reduce_kernel(
    const float* __restrict__ partial, float* __restrict__ out) {
  const int t = threadIdx.x;
  float v = partial[t] + partial[t + 256];
#pragma unroll
  for (int d = 1; d < 64; d <<= 1) v += __shfl_xor(v, d);
  __shared__ float red[4];
  if ((t & 63) == 0) red[t >> 6] = v;
  __syncthreads();
  if (t == 0)
    out[0] = (red[0] + red[1] + red[2] + red[3]) * (1.0f / (float)(NB * (NT - 1)));
}

extern "C" void kernel_launch(void* const* d_in, const int* in_sizes, int n_in,
                              void* d_out, int out_size, void* d_ws, size_t ws_size,
                              hipStream_t stream) {
  (void)in_sizes; (void)n_in; (void)out_size; (void)ws_size;
  const float* x = (const float*)d_in[0];
  float* out = (float*)d_out;
  float* partial = (float*)d_ws;   // 2 KiB

  hipLaunchKernelGGL(fused_kernel, dim3(NB / 2), dim3(512), 0, stream, x, partial);
  hipLaunchKernelGGL(reduce_kernel, dim3(1), dim3(256), 0, stream, partial, out);
}

// Round 7
// 39.106 us; speedup vs baseline: 4.7638x; 1.0025x over previous
//
#include <hip/hip_runtime.h>

// TemporalContrastiveLoss: B=512, T=256, D=256, temperature 0.1.
// Grid = 256 blocks (1/CU), each block does 2 batches sequentially.
// Per batch: S_raw = X*X^T accumulated over 4 K-chunks (64 cols each).
// K-chunk pipeline (double-buffered 32 KB LDS chunk):
//   iter g: {vmwait(counted); cast fp32->bf16; swizzled LDS write chunk g} ;
//           {issue global loads chunk g+1} ; RAW barrier ; {MFMA chunk g}.
// KEY: raw s_barrier + lgkmcnt(0) only -- __syncthreads() would drain
// vmcnt(0) and kill the prefetch (HIP emits full waitcnt before s_barrier).
// Epilogue per batch (g=3,7): inv=rsqrt(diag) from diagonal tiles,
// scaled exp column-sums (symmetric row==col sum), fixed max=10,
// super-diagonal target, per-batch partial. K3: 512->1 mean.

typedef float f32x4  __attribute__((ext_vector_type(4)));
typedef float f32x16 __attribute__((ext_vector_type(16)));
typedef unsigned int u32x2 __attribute__((ext_vector_type(2)));
typedef unsigned int u32x4 __attribute__((ext_vector_type(4)));
typedef __bf16 bf16x8 __attribute__((ext_vector_type(8)));

#define NB 512
#define NT 256
#define ND 256
#define K10L2E 14.42695041f   // 10 * log2(e)

#define MFMA32 __builtin_amdgcn_mfma_f32_32x32x16_bf16

__device__ __forceinline__ unsigned int f2bf_rne(float f) {
  unsigned int u = __float_as_uint(f);
  return (u + 0x7fffu + ((u >> 16) & 1u)) >> 16;
}

// Workgroup barrier that does NOT drain vmcnt: drain own LDS ops
// (lgkmcnt) for cross-wave visibility, then raw s_barrier. Global
// prefetch loads stay in flight across it (unlike __syncthreads).
__device__ __forceinline__ void wg_barrier() {
  asm volatile("s_waitcnt lgkmcnt(0)" ::: "memory");
  __builtin_amdgcn_s_barrier();
  asm volatile("" ::: "memory");
}

// LDS chunk layout: [256 rows][8 slots of 16B], slot = c ^ (row&7)
// (byte ^= (row&7)<<4): spreads the stride-128B column reads across banks.
__global__ __launch_bounds__(512, 2) void fused_kernel(
    const float* __restrict__ x, float* __restrict__ partial) {
  __shared__ u32x4 ck[2 * NT * 8];   // 2 x 32 KiB K-chunk double buffer
  __shared__ float invbuf[NT];       // 1/||x_r|| from MFMA diagonal
  __shared__ float sbuf[NT][5];      // per-col, per-64row-group sum exp(p-10)
  __shared__ float tbuf[NT];         // per-row target logit (x10, normalized)
  __shared__ float redbuf[8];

  const int t    = threadIdx.x;
  const int wave = t >> 6;
  const int lane = t & 63;
  const int lo5  = lane & 31;
  const int hi   = lane >> 5;
  const int sx6  = lo5 & 6;          // (lo5&7)&6
  const int hx   = hi ^ (lo5 & 1);

  // tile assignment: wave w -> tiles (tr, tcA), (tr, tcB); w<4 has diag in A
  const int d   = wave >> 2;
  const int tr  = wave & 3;
  const int tcA = (tr + d) & 3;
  const int tcB = (tr + d + 2) & 3;
  const int R  = tr * 64, CA = tcA * 64, CB = tcB * 64;

  // staging assignment: wave covers rows wave*32..+31, 64 cols per chunk
  const int lrow = lane >> 4;        // 0..3
  const int lcol = lane & 15;        // f32x4 index within 64-col chunk
  const int srow = wave * 32;
  const size_t bstride = (size_t)NT * ND;

  f32x16 aA0, aA1, aA2, aA3, aB0, aB1, aB2, aB3;
#pragma unroll
  for (int e = 0; e < 16; ++e) {
    aA0[e] = 0.f; aA1[e] = 0.f; aA2[e] = 0.f; aA3[e] = 0.f;
    aB0[e] = 0.f; aB1[e] = 0.f; aB2[e] = 0.f; aB3[e] = 0.f;
  }

  f32x4 ld[8];
  {  // prologue: issue chunk g=0 loads (batch blockIdx.x, cols 0..63)
    const float* xb = x + (size_t)blockIdx.x * bstride;
#pragma unroll
    for (int i = 0; i < 8; ++i)
      ld[i] = *(const f32x4*)(xb + (srow + i * 4 + lrow) * ND + lcol * 4);
  }

#pragma unroll 1
  for (int g = 0; g < 8; ++g) {
    u32x4* ckb = &ck[(g & 1) * (NT * 8)];

    // (A) cast + swizzled LDS write of chunk g (waits vmcnt on ld use)
#pragma unroll
    for (int i = 0; i < 8; ++i) {
      const int row = srow + i * 4 + lrow;
      u32x2 o;
      o.x = f2bf_rne(ld[i].x) | (f2bf_rne(ld[i].y) << 16);
      o.y = f2bf_rne(ld[i].z) | (f2bf_rne(ld[i].w) << 16);
      const int slot = (lcol >> 1) ^ (row & 7);
      *(u32x2*)((unsigned int*)(ckb + row * 8 + slot) + (lcol & 1) * 2) = o;
    }

    // (B) issue loads for chunk g+1 (stay in flight across the barrier)
    if (g < 7) {
      const int gn = g + 1;
      const float* xb = x + ((size_t)blockIdx.x + (size_t)(gn >> 2) * 256) * bstride;
      const int kc = (gn & 3) * 64;
#pragma unroll
      for (int i = 0; i < 8; ++i)
        ld[i] = *(const f32x4*)(xb + (srow + i * 4 + lrow) * ND + kc + lcol * 4);
    }

    // (C) chunk g visible to all waves; vmcnt NOT drained
    wg_barrier();

    // (D) MFMA-accumulate chunk g: 4 k-blocks, shared A-frags, 2 tiles
#pragma unroll
    for (int kb = 0; kb < 4; ++kb) {
      const int ko = ((kb * 2) ^ sx6) | hx;   // swizzled slot
      bf16x8 fa0  = __builtin_bit_cast(bf16x8, ckb[(R + lo5) * 8 + ko]);
      bf16x8 fa1  = __builtin_bit_cast(bf16x8, ckb[(R + 32 + lo5) * 8 + ko]);
      bf16x8 fbA0 = __builtin_bit_cast(bf16x8, ckb[(CA + lo5) * 8 + ko]);
      bf16x8 fbA1 = __builtin_bit_cast(bf16x8, ckb[(CA + 32 + lo5) * 8 + ko]);
      bf16x8 fbB0 = __builtin_bit_cast(bf16x8, ckb[(CB + lo5) * 8 + ko]);
      bf16x8 fbB1 = __builtin_bit_cast(bf16x8, ckb[(CB + 32 + lo5) * 8 + ko]);
      aA0 = MFMA32(fa0, fbA0, aA0, 0, 0, 0);
      aA1 = MFMA32(fa0, fbA1, aA1, 0, 0, 0);
      aA2 = MFMA32(fa1, fbA0, aA2, 0, 0, 0);
      aA3 = MFMA32(fa1, fbA1, aA3, 0, 0, 0);
      aB0 = MFMA32(fa0, fbB0, aB0, 0, 0, 0);
      aB1 = MFMA32(fa0, fbB1, aB1, 0, 0, 0);
      aB2 = MFMA32(fa1, fbB0, aB2, 0, 0, 0);
      aB3 = MFMA32(fa1, fbB1, aB3, 0, 0, 0);
    }

    // ---- batch epilogue at g=3 (batch b) and g=7 (batch b+256) ----------
    if ((g & 3) == 3) {
      const int bb = (int)blockIdx.x + (g >> 2) * 256;

      // diagonal tiles (waves 0-3, tile A): publish inv = rsqrt(diag)
      if (d == 0) {
        float dv0 = 1.0f, dv1 = 1.0f;
#pragma unroll
        for (int rg = 0; rg < 16; ++rg) {
          const int rowe = (rg & 3) + 8 * (rg >> 2) + 4 * hi;
          if (rowe == lo5) { dv0 = aA0[rg]; dv1 = aA3[rg]; }
        }
        if (hi == ((lo5 >> 2) & 1)) {
          invbuf[R + lo5]      = rsqrtf(fmaxf(dv0, 1e-24f));
          invbuf[R + 32 + lo5] = rsqrtf(fmaxf(dv1, 1e-24f));
        }
      }
      wg_barrier();   // invbuf[256] valid; batch-2 prefetch stays in flight

      // scaled exp column-sums, tile A (cols CA); row==col sum by symmetry
      {
        const float ic0 = invbuf[CA + lo5] * K10L2E;
        const float ic1 = invbuf[CA + 32 + lo5] * K10L2E;
        float e0 = 0.f, e1 = 0.f;
#pragma unroll
        for (int rg = 0; rg < 16; ++rg) {
          const int rowe = (rg & 3) + 8 * (rg >> 2) + 4 * hi;
          const float ir0 = invbuf[R + rowe], ir1 = invbuf[R + 32 + rowe];
          e0 += exp2f(fmaf(aA0[rg] * ir0, ic0, -K10L2E));
          e0 += exp2f(fmaf(aA2[rg] * ir1, ic0, -K10L2E));
          e1 += exp2f(fmaf(aA1[rg] * ir0, ic1, -K10L2E));
          e1 += exp2f(fmaf(aA3[rg] * ir1, ic1, -K10L2E));
        }
        e0 += __shfl_xor(e0, 32);
        e1 += __shfl_xor(e1, 32);
        if (hi == 0) sbuf[CA + lo5][tr] = e0;
        else         sbuf[CA + 32 + lo5][tr] = e1;
      }
      // tile B (cols CB)
      {
        const float ic0 = invbuf[CB + lo5] * K10L2E;
        const float ic1 = invbuf[CB + 32 + lo5] * K10L2E;
        float e0 = 0.f, e1 = 0.f;
#pragma unroll
        for (int rg = 0; rg < 16; ++rg) {
          const int rowe = (rg & 3) + 8 * (rg >> 2) + 4 * hi;
          const float ir0 = invbuf[R + rowe], ir1 = invbuf[R + 32 + rowe];
          e0 += exp2f(fmaf(aB0[rg] * ir0, ic0, -K10L2E));
          e0 += exp2f(fmaf(aB2[rg] * ir1, ic0, -K10L2E));
          e1 += exp2f(fmaf(aB1[rg] * ir0, ic1, -K10L2E));
          e1 += exp2f(fmaf(aB3[rg] * ir1, ic1, -K10L2E));
        }
        e0 += __shfl_xor(e0, 32);
        e1 += __shfl_xor(e1, 32);
        if (hi == 0) sbuf[CB + lo5][tr] = e0;
        else         sbuf[CB + 32 + lo5][tr] = e1;
      }

      // super-diagonal target (only tiles with tr==tcA or tcA==tr+1)
      if (tcA == tr || tcA == tr + 1) {
#pragma unroll
        for (int ar = 0; ar < 2; ++ar) {
#pragma unroll
          for (int rg = 0; rg < 16; ++rg) {
            const int r = R + ar * 32 + (rg & 3) + 8 * (rg >> 2) + 4 * hi;
            const int tcol = r + 1 - CA;
            if (r < NT - 1 && tcol >= 0 && tcol < 64 && lo5 == (tcol & 31)) {
              const float v = (tcol < 32) ? (ar ? aA2[rg] : aA0[rg])
                                          : (ar ? aA3[rg] : aA1[rg]);
              tbuf[r] = 10.0f * v * invbuf[r] * invbuf[r + 1];
            }
          }
        }
      }
      wg_barrier();   // sbuf/tbuf complete

      // merge 4 row-groups per column, subtract target, block-reduce
      float val = 0.0f;
      if (t < NT - 1) {
        const float s = sbuf[t][0] + sbuf[t][1] + sbuf[t][2] + sbuf[t][3];
        val = 10.0f + __logf(s) - tbuf[t];
      }
#pragma unroll
      for (int dd = 1; dd < 64; dd <<= 1) val += __shfl_xor(val, dd);
      if (lane == 0) redbuf[wave] = val;
      wg_barrier();
      if (t == 0) {
        float s = 0.f;
#pragma unroll
        for (int w = 0; w < 8; ++w) s += redbuf[w];
        partial[bb] = s;
      }

      // reset accumulators for next batch
#pragma unroll
      for (int e = 0; e < 16; ++e) {
        aA0[e] = 0.f; aA1[e] = 0.f; aA2[e] = 0.f; aA3[e] = 0.f;
        aB0[e] = 0.f; aB1[e] = 0.f; aB2[e] = 0.f; aB3[e] = 0.f;
      }
    }
  }
}

// ---------------- K3: 512 partials -> mean (deterministic) ----------------
__global__ __launch_bounds__(256) void reduce_kernel(
    const float* __restrict__ partial, float* __restrict__ out) {
  const int t = threadIdx.x;
  float v = partial[t] + partial[t + 256];
#pragma unroll
  for (int d = 1; d < 64; d <<= 1) v += __shfl_xor(v, d);
  __shared__ float red[4];
  if ((t & 63) == 0) red[t >> 6] = v;
  __syncthreads();
  if (t == 0)
    out[0] = (red[0] + red[1] + red[2] + red[3]) * (1.0f / (float)(NB * (NT - 1)));
}

extern "C" void kernel_launch(void* const* d_in, const int* in_sizes, int n_in,
                              void* d_out, int out_size, void* d_ws, size_t ws_size,
                              hipStream_t stream) {
  (void)in_sizes; (void)n_in; (void)out_size; (void)ws_size;
  const float* x = (const float*)d_in[0];
  float* out = (float*)d_out;
  float* partial = (float*)d_ws;   // 2 KiB

  hipLaunchKernelGGL(fused_kernel, dim3(NB / 2), dim3(512), 0, stream, x, partial);
  hipLaunchKernelGGL(reduce_kernel, dim3(1), dim3(256), 0, stream, partial, out);
}